// Round 12
// baseline (157.003 us; speedup 1.0000x reference)
//
#include <hip/hip_runtime.h>
#include <hip/hip_bf16.h>
#include <math.h>

// Problem constants (from reference)
#define NN  20000      // nodes
#define NE  50000      // directed edges (undirected -> 2*NE)
#define NE2 100000
#define H   32
#define FN  4
#define FE  2
#define FO  4
#define NL  3

#define FRAGS_PER_LAYER (33 * 2)                   // 33 K-steps x 2 n-tiles
#define BVALS_PER_LAYER (FRAGS_PER_LAYER * 512)    // 33792 bf16 per layer

#define NB_PREP ((NL * BVALS_PER_LAYER + 255)/256)  // 396
#define NB_ZERO (NN * H / 4 / 256)                  // 625
#define NB_ENC  ((NN + 255)/256)                    // 79

#define TCHUNKS 196                                 // 256-edge tiles per direction
#define EB      256

typedef __attribute__((ext_vector_type(8))) short short8;
typedef __attribute__((ext_vector_type(4))) float f32x4;
typedef __attribute__((ext_vector_type(4))) unsigned int u32x4;

__device__ __forceinline__ float gelu_f(float x) {
    return 0.5f * x * (1.0f + erff(x * 0.7071067811865476f));
}
__device__ __forceinline__ short f2bf(float x) {
    __hip_bfloat16 b = __float2bfloat16(x);
    return __builtin_bit_cast(short, b);
}
// gfx950 packed f32->bf16 (RNE), 1 inst per 2 values.
__device__ __forceinline__ unsigned int cvt_pk_bf16(float lo, float hi) {
    unsigned int r;
    asm("v_cvt_pk_bf16_f32 %0, %1, %2" : "=v"(r) : "v"(lo), "v"(hi));
    return r;
}

// ---------------------------------------------------------------------------
// Fused prologue: [prep_bfrag | zero_agg | encoder] by blockIdx range.
// (unchanged from R11)
// ---------------------------------------------------------------------------
__global__ __launch_bounds__(256) void prologue(
    const float* __restrict__ x, const float* __restrict__ pm,
    const float* __restrict__ W_in, const float* __restrict__ b_in,
    const float* __restrict__ mW1, const float* __restrict__ mb1,
    const float* __restrict__ mW2, const float* __restrict__ mb2,
    const float* __restrict__ eW2, const float* __restrict__ eb2,
    float* __restrict__ h, float* __restrict__ agg,
    short* __restrict__ Bhi)
{
    int bid = blockIdx.x;
    int tid = threadIdx.x;

    if (bid < NB_PREP) {
        int idx = bid * 256 + tid;
        if (idx >= NL * BVALS_PER_LAYER) return;
        int layer = idx / BVALS_PER_LAYER;
        int rem   = idx - layer * BVALS_PER_LAYER;
        int f      = rem >> 9;
        int within = rem & 511;
        int step = f >> 1, nt = f & 1;
        int l = within >> 3, j = within & 7;
        int p = ((l >> 4) << 3) + j;       // K-slot within step == h index
        int n = nt * 16 + (l & 15);        // output column
        float v;
        if (step < 32) v = eW2[layer * 32768 + step * 1024 + p * 32 + n];
        else           v = eb2[layer * 1024 + p * 32 + n];
        Bhi[idx] = f2bf(v);
        return;
    }
    bid -= NB_PREP;

    if (bid < NB_ZERO) {
        int i = bid * 256 + tid;
        ((float4*)agg)[i] = make_float4(0.f, 0.f, 0.f, 0.f);
        return;
    }
    bid -= NB_ZERO;

    __shared__ float sWin[FN*H], sW1[FN*H], sW2[H*H];
    __shared__ float sbin[H], sb1[H], sb2[H];
    for (int i = tid; i < FN*H; i += 256) { sWin[i] = W_in[i]; sW1[i] = mW1[i]; }
    for (int i = tid; i < H*H; i += 256) sW2[i] = mW2[i];
    if (tid < H) { sbin[tid] = b_in[tid]; sb1[tid] = mb1[tid]; sb2[tid] = mb2[tid]; }
    __syncthreads();
    int n = bid * 256 + tid;
    if (n >= NN) return;
    float xv[FN], pv[FN];
#pragma unroll
    for (int i = 0; i < FN; ++i) { xv[i] = x[n*FN+i]; pv[i] = pm[n*FN+i]; }
    float m[H];
#pragma unroll
    for (int j = 0; j < H; ++j) {
        float a = sb1[j];
#pragma unroll
        for (int i = 0; i < FN; ++i) a += pv[i] * sW1[i*H+j];
        m[j] = gelu_f(a);
    }
#pragma unroll
    for (int j = 0; j < H; ++j) {
        float a = sbin[j] + sb2[j];
#pragma unroll
        for (int i = 0; i < FN; ++i) a += xv[i] * sWin[i*H+j];
        float s = 0.f;
#pragma unroll
        for (int k = 0; k < H; ++k) s += m[k] * sW2[k*H+j];
        h[n*H+j] = a + s;
    }
}

// ---------------------------------------------------------------------------
// Edge pass: 256 threads = 4 waves; 64 edges per wave (4 MFMA M-tiles).
// Latency-chain restructure vs R11:
//   - B fragments prefetched 4 steps deep (5-pair register rotation);
//     first 4 pairs issued at kernel entry, hidden under t-gen.
//   - h[src] gather issued immediately after the src barrier, consumed
//     after t-gen (erf block covers its latency).
// Numerics bit-identical to R11.
// ---------------------------------------------------------------------------
__global__ __launch_bounds__(256) void edge_pass(
    const float* __restrict__ h,
    const int* __restrict__ ei,           // [2, NE] int32
    const float* __restrict__ ea,         // [NE, 2]
    const float* __restrict__ w1,         // eW1 + l*FE*H : [2][32]
    const float* __restrict__ b1,         // eb1 + l*H    : [32]
    const short* __restrict__ Bhi,        // layer fragment stream (bf16)
    float* __restrict__ agg)              // [NN, 32]
{
    __shared__ float t_lds[32][EB];       // 32 KB  [k][edge-in-block]
    __shared__ int src_lds[EB], dst_lds[EB];
    __shared__ float sw[3*H];             // w1 row0, w1 row1, b1

    int tid = threadIdx.x;
    int bid = blockIdx.x;
    bool half2 = bid >= TCHUNKS;
    int er_base = (half2 ? bid - TCHUNKS : bid) * EB;

    int lane = tid & 63;

    // --- issue B-fragment loads for steps 0..3 right away (no dependencies)
    const short8* F = (const short8*)Bhi;     // frag(step,nt) = F[step*128 + nt*64 + lane]
    short8 P0a = F[lane],         P0b = F[64 + lane];
    short8 P1a = F[128 + lane],   P1b = F[192 + lane];
    short8 P2a = F[256 + lane],   P2b = F[320 + lane];
    short8 P3a = F[384 + lane],   P3b = F[448 + lane];
    short8 P4a, P4b;

    if (tid < H) {
        sw[tid]       = w1[tid];
        sw[H + tid]   = w1[H + tid];
        sw[2*H + tid] = b1[tid];
    }
    {   // src/dst for this block's 256 edges
        int er = er_base + tid;
        int erc = er < NE ? er : NE - 1;
        int s, d;
        if (half2) { s = ei[NE + erc]; d = ei[erc]; }
        else       { s = ei[erc];      d = ei[NE + erc]; }
        bool v = er < NE;
        src_lds[tid] = v ? s : 0;
        dst_lds[tid] = v ? d : 0;
    }
    __syncthreads();

    int wv = tid >> 6;
    int lg = lane >> 4, lm = lane & 15;
    int jbase = wv * 64;

    // --- issue h[src] gather now; consumed after t-gen (latency hidden)
    float4 hg[4][2];
#pragma unroll
    for (int m = 0; m < 4; ++m) {
        int s = src_lds[jbase + m*16 + lm];
        const float4* hp = (const float4*)(h + (size_t)s*H + lg*8);
        hg[m][0] = hp[0];
        hg[m][1] = hp[1];
    }

    {   // t-gen, all threads parallel: t[k][tid] = gelu(ea[er]@w1 + b1)[k]
        int er = er_base + tid;
        int erc = er < NE ? er : NE - 1;
        float2 av = *(const float2*)(ea + (size_t)erc * 2);
#pragma unroll 8
        for (int k = 0; k < 32; ++k) {
            t_lds[k][tid] = gelu_f(av.x * sw[k] + av.y * sw[H + k] + sw[2*H + k]);
        }
    }
    __syncthreads();

    float hs[4][8];
#pragma unroll
    for (int m = 0; m < 4; ++m) {
        hs[m][0]=hg[m][0].x; hs[m][1]=hg[m][0].y; hs[m][2]=hg[m][0].z; hs[m][3]=hg[m][0].w;
        hs[m][4]=hg[m][1].x; hs[m][5]=hg[m][1].y; hs[m][6]=hg[m][1].z; hs[m][7]=hg[m][1].w;
    }

    f32x4 acc[4][2];
#pragma unroll
    for (int m = 0; m < 4; ++m) {
        acc[m][0] = (f32x4){0.f,0.f,0.f,0.f};
        acc[m][1] = (f32x4){0.f,0.f,0.f,0.f};
    }

#pragma unroll 1
    for (int step = 0; step < 32; ++step) {
        if (step + 4 <= 32) {                 // issue loads for step+4
            int fo = (step + 4) * 128 + lane;
            P4a = F[fo]; P4b = F[fo + 64];
        }
#pragma unroll
        for (int m = 0; m < 4; ++m) {
            float tv = t_lds[step][jbase + m*16 + lm];
            u32x4 pr;
            pr[0] = cvt_pk_bf16(tv * hs[m][0], tv * hs[m][1]);
            pr[1] = cvt_pk_bf16(tv * hs[m][2], tv * hs[m][3]);
            pr[2] = cvt_pk_bf16(tv * hs[m][4], tv * hs[m][5]);
            pr[3] = cvt_pk_bf16(tv * hs[m][6], tv * hs[m][7]);
            short8 a = __builtin_bit_cast(short8, pr);
            acc[m][0] = __builtin_amdgcn_mfma_f32_16x16x32_bf16(a, P0a, acc[m][0], 0, 0, 0);
            acc[m][1] = __builtin_amdgcn_mfma_f32_16x16x32_bf16(a, P0b, acc[m][1], 0, 0, 0);
        }
        P0a = P1a; P0b = P1b;
        P1a = P2a; P1b = P2b;
        P2a = P3a; P2b = P3b;
        P3a = P4a; P3b = P4b;
    }
    // peeled bias step (t == 1): uses step-32 frags now in P0
#pragma unroll
    for (int m = 0; m < 4; ++m) {
        u32x4 pr;
        pr[0] = cvt_pk_bf16(hs[m][0], hs[m][1]);
        pr[1] = cvt_pk_bf16(hs[m][2], hs[m][3]);
        pr[2] = cvt_pk_bf16(hs[m][4], hs[m][5]);
        pr[3] = cvt_pk_bf16(hs[m][6], hs[m][7]);
        short8 a = __builtin_bit_cast(short8, pr);
        acc[m][0] = __builtin_amdgcn_mfma_f32_16x16x32_bf16(a, P0a, acc[m][0], 0, 0, 0);
        acc[m][1] = __builtin_amdgcn_mfma_f32_16x16x32_bf16(a, P0b, acc[m][1], 0, 0, 0);
    }

    // C/D layout: col = lane&15, row = (lane>>4)*4 + reg
#pragma unroll
    for (int m = 0; m < 4; ++m) {
#pragma unroll
        for (int r = 0; r < 4; ++r) {
            int erow = jbase + m*16 + lg*4 + r;
            if (er_base + erow < NE) {
                int d = dst_lds[erow];
                atomicAdd(agg + (size_t)d*H + lm,      acc[m][0][r]);
                atomicAdd(agg + (size_t)d*H + 16 + lm, acc[m][1][r]);
            }
        }
    }
}

// ---------------------------------------------------------------------------
// Node update: hc = agg + h@Wr + cb; LayerNorm; h += gelu(hn).
// Non-last: writes h, re-zeros agg. Last: fuses decoder, writes out.
// (unchanged from R11)
// ---------------------------------------------------------------------------
__global__ __launch_bounds__(256) void node_update(
    float* __restrict__ h, float* __restrict__ agg,
    const float* __restrict__ wr, const float* __restrict__ cb,
    const float* __restrict__ gamma, const float* __restrict__ beta,
    const float* __restrict__ dW1, const float* __restrict__ db1,
    const float* __restrict__ dW2, const float* __restrict__ db2,
    float* __restrict__ out, int last)
{
    __shared__ float swr[H*H], sW1d[H*H], sW2d[H*FO];
    __shared__ float scb[H], sg[H], sb[H], sb1d[H], sb2d[FO];
    int tid = threadIdx.x;
    for (int i = tid; i < H*H; i += 256) { swr[i] = wr[i]; sW1d[i] = dW1[i]; }
    for (int i = tid; i < H*FO; i += 256) sW2d[i] = dW2[i];
    if (tid < H) { scb[tid] = cb[tid]; sg[tid] = gamma[tid]; sb[tid] = beta[tid]; sb1d[tid] = db1[tid]; }
    if (tid < FO) sb2d[tid] = db2[tid];
    __syncthreads();
    int n = blockIdx.x * 256 + tid;
    if (n >= NN) return;

    float hv[H], hc[H];
#pragma unroll
    for (int q = 0; q < 8; ++q) {
        float4 v = ((const float4*)(h + n*H))[q];
        hv[q*4+0]=v.x; hv[q*4+1]=v.y; hv[q*4+2]=v.z; hv[q*4+3]=v.w;
        float4 g = ((const float4*)(agg + n*H))[q];
        hc[q*4+0]=g.x; hc[q*4+1]=g.y; hc[q*4+2]=g.z; hc[q*4+3]=g.w;
    }
#pragma unroll
    for (int o = 0; o < H; ++o) hc[o] += scb[o];
#pragma unroll
    for (int k = 0; k < H; ++k) {
        float hk = hv[k];
#pragma unroll
        for (int o = 0; o < H; ++o) hc[o] += hk * swr[k*H+o];
    }
    float mu = 0.f;
#pragma unroll
    for (int o = 0; o < H; ++o) mu += hc[o];
    mu *= (1.0f/H);
    float var = 0.f;
#pragma unroll
    for (int o = 0; o < H; ++o) { float d = hc[o]-mu; var += d*d; }
    var *= (1.0f/H);
    float rs = rsqrtf(var + 1e-5f);
#pragma unroll
    for (int o = 0; o < H; ++o) {
        float hn = (hc[o]-mu)*rs*sg[o] + sb[o];
        hv[o] += gelu_f(hn);
    }

    if (!last) {
#pragma unroll
        for (int q = 0; q < 8; ++q) {
            ((float4*)(h + n*H))[q]   = make_float4(hv[q*4+0], hv[q*4+1], hv[q*4+2], hv[q*4+3]);
            ((float4*)(agg + n*H))[q] = make_float4(0.f, 0.f, 0.f, 0.f);
        }
    } else {
        // fused decoder: out = gelu(hv@dW1+db1)@dW2 + db2
        float g[H];
#pragma unroll
        for (int j = 0; j < H; ++j) {
            float a = sb1d[j];
#pragma unroll
            for (int k = 0; k < H; ++k) a += hv[k] * sW1d[k*H+j];
            g[j] = gelu_f(a);
        }
#pragma unroll
        for (int o = 0; o < FO; ++o) {
            float a = sb2d[o];
#pragma unroll
            for (int k = 0; k < H; ++k) a += g[k] * sW2d[k*FO+o];
            out[n*FO+o] = a;
        }
    }
}

// ---------------------------------------------------------------------------
extern "C" void kernel_launch(void* const* d_in, const int* in_sizes, int n_in,
                              void* d_out, int out_size, void* d_ws, size_t ws_size,
                              hipStream_t stream)
{
    const float* x    = (const float*)d_in[0];
    const float* pm   = (const float*)d_in[1];
    const int*   ei   = (const int*)d_in[2];      // int inputs arrive as int32
    const float* ea   = (const float*)d_in[3];
    const float* W_in = (const float*)d_in[4];
    const float* b_in = (const float*)d_in[5];
    const float* mW1  = (const float*)d_in[6];
    const float* mb1  = (const float*)d_in[7];
    const float* mW2  = (const float*)d_in[8];
    const float* mb2  = (const float*)d_in[9];
    const float* eW1  = (const float*)d_in[10];
    const float* eb1  = (const float*)d_in[11];
    const float* eW2  = (const float*)d_in[12];
    const float* eb2  = (const float*)d_in[13];
    const float* Wr   = (const float*)d_in[14];
    const float* cb   = (const float*)d_in[15];
    const float* gm   = (const float*)d_in[16];
    const float* bt   = (const float*)d_in[17];
    const float* dW1  = (const float*)d_in[18];
    const float* db1  = (const float*)d_in[19];
    const float* dW2  = (const float*)d_in[20];
    const float* db2  = (const float*)d_in[21];
    float* out = (float*)d_out;

    float* h   = (float*)d_ws;                    // NN*H f32
    float* agg = h + NN*H;                        // NN*H f32
    short* Bhi = (short*)(agg + NN*H);            // NL*33792 bf16

    prologue<<<NB_PREP + NB_ZERO + NB_ENC, 256, 0, stream>>>(
        x, pm, W_in, b_in, mW1, mb1, mW2, mb2, eW2, eb2, h, agg, Bhi);

    for (int l = 0; l < NL; ++l) {
        edge_pass<<<2*TCHUNKS, 256, 0, stream>>>(
            h, ei, ea, eW1 + l*FE*H, eb1 + l*H,
            Bhi + l*BVALS_PER_LAYER, agg);
        node_update<<<(NN + 255)/256, 256, 0, stream>>>(
            h, agg, Wr + l*H*H, cb + l*H, gm + l*H, bt + l*H,
            dW1, db1, dW2, db2, out, l == NL-1);
    }
}

// Round 13
// 155.418 us; speedup vs baseline: 1.0102x; 1.0102x over previous
//
#include <hip/hip_runtime.h>
#include <hip/hip_bf16.h>
#include <math.h>

// Problem constants (from reference)
#define NN  20000      // nodes
#define NE  50000      // directed edges (undirected -> 2*NE)
#define NE2 100000
#define H   32
#define FN  4
#define FE  2
#define FO  4
#define NL  3

#define FRAGS_PER_LAYER (33 * 2)                   // 33 K-steps x 2 n-tiles
#define BVALS_PER_LAYER (FRAGS_PER_LAYER * 512)    // 33792 bf16 per layer

#define NB_PREP ((NL * BVALS_PER_LAYER + 255)/256)  // 396
#define NB_ZERO (NN * H / 4 / 256)                  // 625
#define NB_ENC  ((NN + 255)/256)                    // 79

#define EPB     64                                  // original edges per block
#define NB_EDGE ((NE + EPB - 1) / EPB)              // 782 blocks (fwd+rev folded)

typedef __attribute__((ext_vector_type(8))) short short8;
typedef __attribute__((ext_vector_type(4))) float f32x4;
typedef __attribute__((ext_vector_type(4))) unsigned int u32x4;

__device__ __forceinline__ float gelu_f(float x) {
    return 0.5f * x * (1.0f + erff(x * 0.7071067811865476f));
}
__device__ __forceinline__ short f2bf(float x) {
    __hip_bfloat16 b = __float2bfloat16(x);
    return __builtin_bit_cast(short, b);
}
// gfx950 packed f32->bf16 (RNE), 1 inst per 2 values.
__device__ __forceinline__ unsigned int cvt_pk_bf16(float lo, float hi) {
    unsigned int r;
    asm("v_cvt_pk_bf16_f32 %0, %1, %2" : "=v"(r) : "v"(lo), "v"(hi));
    return r;
}

// ---------------------------------------------------------------------------
// Fused prologue: [prep_bfrag | zero_agg | encoder] by blockIdx range.
// (unchanged from R11)
// ---------------------------------------------------------------------------
__global__ __launch_bounds__(256) void prologue(
    const float* __restrict__ x, const float* __restrict__ pm,
    const float* __restrict__ W_in, const float* __restrict__ b_in,
    const float* __restrict__ mW1, const float* __restrict__ mb1,
    const float* __restrict__ mW2, const float* __restrict__ mb2,
    const float* __restrict__ eW2, const float* __restrict__ eb2,
    float* __restrict__ h, float* __restrict__ agg,
    short* __restrict__ Bhi)
{
    int bid = blockIdx.x;
    int tid = threadIdx.x;

    if (bid < NB_PREP) {
        int idx = bid * 256 + tid;
        if (idx >= NL * BVALS_PER_LAYER) return;
        int layer = idx / BVALS_PER_LAYER;
        int rem   = idx - layer * BVALS_PER_LAYER;
        int f      = rem >> 9;
        int within = rem & 511;
        int step = f >> 1, nt = f & 1;
        int l = within >> 3, j = within & 7;
        int p = ((l >> 4) << 3) + j;       // K-slot within step == h index
        int n = nt * 16 + (l & 15);        // output column
        float v;
        if (step < 32) v = eW2[layer * 32768 + step * 1024 + p * 32 + n];
        else           v = eb2[layer * 1024 + p * 32 + n];
        Bhi[idx] = f2bf(v);
        return;
    }
    bid -= NB_PREP;

    if (bid < NB_ZERO) {
        int i = bid * 256 + tid;
        ((float4*)agg)[i] = make_float4(0.f, 0.f, 0.f, 0.f);
        return;
    }
    bid -= NB_ZERO;

    __shared__ float sWin[FN*H], sW1[FN*H], sW2[H*H];
    __shared__ float sbin[H], sb1[H], sb2[H];
    for (int i = tid; i < FN*H; i += 256) { sWin[i] = W_in[i]; sW1[i] = mW1[i]; }
    for (int i = tid; i < H*H; i += 256) sW2[i] = mW2[i];
    if (tid < H) { sbin[tid] = b_in[tid]; sb1[tid] = mb1[tid]; sb2[tid] = mb2[tid]; }
    __syncthreads();
    int n = bid * 256 + tid;
    if (n >= NN) return;
    float xv[FN], pv[FN];
#pragma unroll
    for (int i = 0; i < FN; ++i) { xv[i] = x[n*FN+i]; pv[i] = pm[n*FN+i]; }
    float m[H];
#pragma unroll
    for (int j = 0; j < H; ++j) {
        float a = sb1[j];
#pragma unroll
        for (int i = 0; i < FN; ++i) a += pv[i] * sW1[i*H+j];
        m[j] = gelu_f(a);
    }
#pragma unroll
    for (int j = 0; j < H; ++j) {
        float a = sbin[j] + sb2[j];
#pragma unroll
        for (int i = 0; i < FN; ++i) a += xv[i] * sWin[i*H+j];
        float s = 0.f;
#pragma unroll
        for (int k = 0; k < H; ++k) s += m[k] * sW2[k*H+j];
        h[n*H+j] = a + s;
    }
}

// ---------------------------------------------------------------------------
// Edge pass, direction-folded: one block = 64 ORIGINAL edges -> 128 edge
// instances (fwd + rev), so t (gelu/erf) is computed ONCE per edge instead
// of twice, and ei/ea loads halve. 128 threads = 2 waves x 4 MFMA M-tiles.
// B bf16 depth-2 register rotation (R11 config). atomicAdd scatter.
// Numerics bit-identical to R11.
// ---------------------------------------------------------------------------
__global__ __launch_bounds__(128) void edge_pass(
    const float* __restrict__ h,
    const int* __restrict__ ei,           // [2, NE] int32
    const float* __restrict__ ea,         // [NE, 2]
    const float* __restrict__ w1,         // eW1 + l*FE*H : [2][32]
    const float* __restrict__ b1,         // eb1 + l*H    : [32]
    const short* __restrict__ Bhi,        // layer fragment stream (bf16)
    float* __restrict__ agg)              // [NN, 32]
{
    __shared__ float t_lds[32][EPB];      // 8 KB  [k][original edge in block]
    __shared__ int src_lds[2*EPB], dst_lds[2*EPB];
    __shared__ float sw[3*H];             // w1 row0, w1 row1, b1

    int tid = threadIdx.x;                // 0..127
    int bid = blockIdx.x;
    int er_base = bid * EPB;

    if (tid < 2*H)      sw[tid] = w1[tid];
    else if (tid < 3*H) sw[tid] = b1[tid - 2*H];

    {   // src/dst for 128 instances: tid<64 fwd, tid>=64 rev (same er)
        int e  = tid & 63;
        int er = er_base + e;
        int erc = er < NE ? er : NE - 1;
        int a0 = ei[erc], a1 = ei[NE + erc];
        bool fwd = tid < 64;
        src_lds[tid] = fwd ? a0 : a1;
        dst_lds[tid] = fwd ? a1 : a0;
    }
    __syncthreads();

    {   // t-gen ONCE per original edge: 16 gelu per thread
        int e  = tid & 63;
        int kq = tid >> 6;                // 0 or 1 -> k in [kq*16, kq*16+16)
        int er = er_base + e;
        int erc = er < NE ? er : NE - 1;
        float2 av = *(const float2*)(ea + (size_t)erc * 2);
#pragma unroll
        for (int kk = 0; kk < 16; ++kk) {
            int k = kq * 16 + kk;
            t_lds[k][e] = gelu_f(av.x * sw[k] + av.y * sw[H + k] + sw[2*H + k]);
        }
    }
    __syncthreads();

    int wv = tid >> 6, lane = tid & 63;   // wv: 0 = fwd instances, 1 = rev
    int lg = lane >> 4, lm = lane & 15;
    int jbase = wv * 64;                  // instance base

    // Per-lane h[src] slice: 8 f32 features for each of 4 M-tile instances.
    float hs[4][8];
#pragma unroll
    for (int m = 0; m < 4; ++m) {
        int s = src_lds[jbase + m*16 + lm];
        const float4* hp = (const float4*)(h + (size_t)s*H + lg*8);
        float4 u0 = hp[0], u1 = hp[1];
        hs[m][0]=u0.x; hs[m][1]=u0.y; hs[m][2]=u0.z; hs[m][3]=u0.w;
        hs[m][4]=u1.x; hs[m][5]=u1.y; hs[m][6]=u1.z; hs[m][7]=u1.w;
    }

    f32x4 acc[4][2];
#pragma unroll
    for (int m = 0; m < 4; ++m) {
        acc[m][0] = (f32x4){0.f,0.f,0.f,0.f};
        acc[m][1] = (f32x4){0.f,0.f,0.f,0.f};
    }

    // B fragments, depth-2 register rotation (R11 config).
    const short8* F = (const short8*)Bhi;     // frag(step,nt) = F[step*128 + nt*64 + lane]
    short8 A0 = F[lane],        A1 = F[64 + lane];
    short8 B0 = F[128 + lane],  B1 = F[192 + lane];
    short8 C0, C1;

#pragma unroll 1
    for (int step = 0; step < 32; ++step) {
        if (step + 2 <= 32) {                 // issue loads for step+2
            int fo = (step + 2) * 128 + lane;
            C0 = F[fo]; C1 = F[fo + 64];
        }
#pragma unroll
        for (int m = 0; m < 4; ++m) {
            float tv = t_lds[step][m*16 + lm];    // (jbase+m*16+lm) & 63 == m*16+lm
            u32x4 pr;
            pr[0] = cvt_pk_bf16(tv * hs[m][0], tv * hs[m][1]);
            pr[1] = cvt_pk_bf16(tv * hs[m][2], tv * hs[m][3]);
            pr[2] = cvt_pk_bf16(tv * hs[m][4], tv * hs[m][5]);
            pr[3] = cvt_pk_bf16(tv * hs[m][6], tv * hs[m][7]);
            short8 a = __builtin_bit_cast(short8, pr);
            acc[m][0] = __builtin_amdgcn_mfma_f32_16x16x32_bf16(a, A0, acc[m][0], 0, 0, 0);
            acc[m][1] = __builtin_amdgcn_mfma_f32_16x16x32_bf16(a, A1, acc[m][1], 0, 0, 0);
        }
        A0 = B0; A1 = B1; B0 = C0; B1 = C1;
    }
    // peeled bias step (t == 1): uses step-32 frags now in A0/A1
#pragma unroll
    for (int m = 0; m < 4; ++m) {
        u32x4 pr;
        pr[0] = cvt_pk_bf16(hs[m][0], hs[m][1]);
        pr[1] = cvt_pk_bf16(hs[m][2], hs[m][3]);
        pr[2] = cvt_pk_bf16(hs[m][4], hs[m][5]);
        pr[3] = cvt_pk_bf16(hs[m][6], hs[m][7]);
        short8 a = __builtin_bit_cast(short8, pr);
        acc[m][0] = __builtin_amdgcn_mfma_f32_16x16x32_bf16(a, A0, acc[m][0], 0, 0, 0);
        acc[m][1] = __builtin_amdgcn_mfma_f32_16x16x32_bf16(a, A1, acc[m][1], 0, 0, 0);
    }

    // C/D layout: col = lane&15, row = (lane>>4)*4 + reg
#pragma unroll
    for (int m = 0; m < 4; ++m) {
#pragma unroll
        for (int r = 0; r < 4; ++r) {
            int j = jbase + m*16 + lg*4 + r;      // instance
            if (er_base + (j & 63) < NE) {
                int d = dst_lds[j];
                atomicAdd(agg + (size_t)d*H + lm,      acc[m][0][r]);
                atomicAdd(agg + (size_t)d*H + 16 + lm, acc[m][1][r]);
            }
        }
    }
}

// ---------------------------------------------------------------------------
// Node update: hc = agg + h@Wr + cb; LayerNorm; h += gelu(hn).
// Non-last: writes h, re-zeros agg. Last: fuses decoder, writes out.
// (unchanged from R11)
// ---------------------------------------------------------------------------
__global__ __launch_bounds__(256) void node_update(
    float* __restrict__ h, float* __restrict__ agg,
    const float* __restrict__ wr, const float* __restrict__ cb,
    const float* __restrict__ gamma, const float* __restrict__ beta,
    const float* __restrict__ dW1, const float* __restrict__ db1,
    const float* __restrict__ dW2, const float* __restrict__ db2,
    float* __restrict__ out, int last)
{
    __shared__ float swr[H*H], sW1d[H*H], sW2d[H*FO];
    __shared__ float scb[H], sg[H], sb[H], sb1d[H], sb2d[FO];
    int tid = threadIdx.x;
    for (int i = tid; i < H*H; i += 256) { swr[i] = wr[i]; sW1d[i] = dW1[i]; }
    for (int i = tid; i < H*FO; i += 256) sW2d[i] = dW2[i];
    if (tid < H) { scb[tid] = cb[tid]; sg[tid] = gamma[tid]; sb[tid] = beta[tid]; sb1d[tid] = db1[tid]; }
    if (tid < FO) sb2d[tid] = db2[tid];
    __syncthreads();
    int n = blockIdx.x * 256 + tid;
    if (n >= NN) return;

    float hv[H], hc[H];
#pragma unroll
    for (int q = 0; q < 8; ++q) {
        float4 v = ((const float4*)(h + n*H))[q];
        hv[q*4+0]=v.x; hv[q*4+1]=v.y; hv[q*4+2]=v.z; hv[q*4+3]=v.w;
        float4 g = ((const float4*)(agg + n*H))[q];
        hc[q*4+0]=g.x; hc[q*4+1]=g.y; hc[q*4+2]=g.z; hc[q*4+3]=g.w;
    }
#pragma unroll
    for (int o = 0; o < H; ++o) hc[o] += scb[o];
#pragma unroll
    for (int k = 0; k < H; ++k) {
        float hk = hv[k];
#pragma unroll
        for (int o = 0; o < H; ++o) hc[o] += hk * swr[k*H+o];
    }
    float mu = 0.f;
#pragma unroll
    for (int o = 0; o < H; ++o) mu += hc[o];
    mu *= (1.0f/H);
    float var = 0.f;
#pragma unroll
    for (int o = 0; o < H; ++o) { float d = hc[o]-mu; var += d*d; }
    var *= (1.0f/H);
    float rs = rsqrtf(var + 1e-5f);
#pragma unroll
    for (int o = 0; o < H; ++o) {
        float hn = (hc[o]-mu)*rs*sg[o] + sb[o];
        hv[o] += gelu_f(hn);
    }

    if (!last) {
#pragma unroll
        for (int q = 0; q < 8; ++q) {
            ((float4*)(h + n*H))[q]   = make_float4(hv[q*4+0], hv[q*4+1], hv[q*4+2], hv[q*4+3]);
            ((float4*)(agg + n*H))[q] = make_float4(0.f, 0.f, 0.f, 0.f);
        }
    } else {
        // fused decoder: out = gelu(hv@dW1+db1)@dW2 + db2
        float g[H];
#pragma unroll
        for (int j = 0; j < H; ++j) {
            float a = sb1d[j];
#pragma unroll
            for (int k = 0; k < H; ++k) a += hv[k] * sW1d[k*H+j];
            g[j] = gelu_f(a);
        }
#pragma unroll
        for (int o = 0; o < FO; ++o) {
            float a = sb2d[o];
#pragma unroll
            for (int k = 0; k < H; ++k) a += g[k] * sW2d[k*FO+o];
            out[n*FO+o] = a;
        }
    }
}

// ---------------------------------------------------------------------------
extern "C" void kernel_launch(void* const* d_in, const int* in_sizes, int n_in,
                              void* d_out, int out_size, void* d_ws, size_t ws_size,
                              hipStream_t stream)
{
    const float* x    = (const float*)d_in[0];
    const float* pm   = (const float*)d_in[1];
    const int*   ei   = (const int*)d_in[2];      // int inputs arrive as int32
    const float* ea   = (const float*)d_in[3];
    const float* W_in = (const float*)d_in[4];
    const float* b_in = (const float*)d_in[5];
    const float* mW1  = (const float*)d_in[6];
    const float* mb1  = (const float*)d_in[7];
    const float* mW2  = (const float*)d_in[8];
    const float* mb2  = (const float*)d_in[9];
    const float* eW1  = (const float*)d_in[10];
    const float* eb1  = (const float*)d_in[11];
    const float* eW2  = (const float*)d_in[12];
    const float* eb2  = (const float*)d_in[13];
    const float* Wr   = (const float*)d_in[14];
    const float* cb   = (const float*)d_in[15];
    const float* gm   = (const float*)d_in[16];
    const float* bt   = (const float*)d_in[17];
    const float* dW1  = (const float*)d_in[18];
    const float* db1  = (const float*)d_in[19];
    const float* dW2  = (const float*)d_in[20];
    const float* db2  = (const float*)d_in[21];
    float* out = (float*)d_out;

    float* h   = (float*)d_ws;                    // NN*H f32
    float* agg = h + NN*H;                        // NN*H f32
    short* Bhi = (short*)(agg + NN*H);            // NL*33792 bf16

    prologue<<<NB_PREP + NB_ZERO + NB_ENC, 256, 0, stream>>>(
        x, pm, W_in, b_in, mW1, mb1, mW2, mb2, eW2, eb2, h, agg, Bhi);

    for (int l = 0; l < NL; ++l) {
        edge_pass<<<NB_EDGE, 128, 0, stream>>>(
            h, ei, ea, eW1 + l*FE*H, eb1 + l*H,
            Bhi + l*BVALS_PER_LAYER, agg);
        node_update<<<(NN + 255)/256, 256, 0, stream>>>(
            h, agg, Wr + l*H*H, cb + l*H, gm + l*H, bt + l*H,
            dW1, db1, dW2, db2, out, l == NL-1);
    }
}